// Round 5
// baseline (953.984 us; speedup 1.0000x reference)
//
#include <hip/hip_runtime.h>
#include <hip/hip_bf16.h>
#include <math.h>

#define N_NODES 20000
#define E2      240000     // directed edges (2E)
#define EP      120000     // positive edges
#define ENEG    600000     // negative edges
#define ETOT    720000     // EP + ENEG

typedef __attribute__((ext_vector_type(8))) short bf16x8;
typedef __attribute__((ext_vector_type(4))) float f32x4;

__device__ __forceinline__ float logsigf(float x) {
    return fminf(x, 0.0f) - log1pf(expf(-fabsf(x)));
}

__device__ __forceinline__ unsigned short f2bf(float f) {
    unsigned u = __float_as_uint(f);
    u += 0x7FFF + ((u >> 16) & 1);   // RNE
    return (unsigned short)(u >> 16);
}

// ---------------- K1: m1 = x @ W1   [20000,256] @ [256,256] ----------------
__global__ __launch_bounds__(256) void k_mm_xW1(const float* __restrict__ x,
                                                const float* __restrict__ W1,
                                                float* __restrict__ m1) {
    __shared__ float xl[8 * 256];
    const int tid = threadIdx.x;
    const long base = (long)blockIdx.x * 8 * 256;
    const float4* src = (const float4*)(x + base);
    float4* dst = (float4*)xl;
    for (int i = tid; i < 512; i += 256) dst[i] = src[i];
    __syncthreads();
    float acc[8] = {0.f,0.f,0.f,0.f,0.f,0.f,0.f,0.f};
    for (int k = 0; k < 256; k += 4) {
        const float w0 = W1[(k + 0) * 256 + tid];
        const float w1 = W1[(k + 1) * 256 + tid];
        const float w2 = W1[(k + 2) * 256 + tid];
        const float w3 = W1[(k + 3) * 256 + tid];
#pragma unroll
        for (int r = 0; r < 8; ++r) {
            const float4 xv = *(const float4*)&xl[r * 256 + k];
            acc[r] += xv.x * w0 + xv.y * w1 + xv.z * w2 + xv.w * w3;
        }
    }
#pragma unroll
    for (int r = 0; r < 8; ++r) m1[base + r * 256 + tid] = acc[r];
}

// ---------------- CSR build: histogram -> scan -> fill ----------------
__global__ void k_hist(const int* __restrict__ dsts, int* __restrict__ cnt, int nE) {
    const int e = blockIdx.x * 256 + threadIdx.x;
    if (e < nE) atomicAdd(&cnt[dsts[e]], 1);
}

__global__ __launch_bounds__(1024) void k_scan(const int* __restrict__ cnt,
                                               int* __restrict__ rs,
                                               int* __restrict__ cur, int n) {
    __shared__ int wexc[16];
    __shared__ int s_carry, s_tot;
    const int tid = threadIdx.x, lane = tid & 63, wid = tid >> 6;
    if (tid == 0) s_carry = 0;
    __syncthreads();
    for (int base = 0; base < n; base += 1024) {
        const int i = base + tid;
        const int v = (i < n) ? cnt[i] : 0;
        int x = v;
#pragma unroll
        for (int d = 1; d < 64; d <<= 1) {
            const int t = __shfl_up(x, d, 64);
            if (lane >= d) x += t;
        }
        if (lane == 63) wexc[wid] = x;
        __syncthreads();
        if (tid == 0) {
            int a = 0;
#pragma unroll
            for (int k = 0; k < 16; ++k) { const int t = wexc[k]; wexc[k] = a; a += t; }
            s_tot = a;
        }
        __syncthreads();
        const int excl = s_carry + wexc[wid] + x - v;
        if (i < n) { rs[i] = excl; cur[i] = excl; }
        __syncthreads();
        if (tid == 0) s_carry += s_tot;
        __syncthreads();
    }
    if (tid == 0) rs[n] = s_carry;
}

__global__ void k_fill(const int* __restrict__ srcs, const int* __restrict__ dsts,
                       int* __restrict__ cur, int* __restrict__ adj, int nE) {
    const int e = blockIdx.x * 256 + threadIdx.x;
    if (e < nE) {
        const int d = dsts[e];
        const int p = atomicAdd(&cur[d], 1);
        adj[p] = srcs[e];
    }
}

__global__ void k_dis(const int* __restrict__ rsP, float* __restrict__ dis) {
    const int i = blockIdx.x * 256 + threadIdx.x;
    if (i < N_NODES) dis[i] = rsqrtf((float)(rsP[i + 1] - rsP[i] + 1));
}

// ---- K2: h1 = relu(LN(segsum(m1[adj]) + b1)); gather per node (dim 256) ----
__global__ __launch_bounds__(256) void k_gather_ln(const float* __restrict__ m1,
                                                   const int* __restrict__ rs,
                                                   const int* __restrict__ adj,
                                                   const float* __restrict__ b1,
                                                   const float* __restrict__ g1,
                                                   const float* __restrict__ bt1,
                                                   float* __restrict__ h1) {
    const int wid = threadIdx.x >> 6, lane = threadIdx.x & 63;
    const int n = blockIdx.x * 4 + wid;
    const int beg = rs[n], end = rs[n + 1];
    float4 a0 = {0.f,0.f,0.f,0.f}, a1 = {0.f,0.f,0.f,0.f};
    int j = beg;
    for (; j + 1 < end; j += 2) {
        const int s0 = adj[j], s1 = adj[j + 1];
        const float4 u = *(const float4*)(m1 + (long)s0 * 256 + lane * 4);
        const float4 v = *(const float4*)(m1 + (long)s1 * 256 + lane * 4);
        a0.x += u.x; a0.y += u.y; a0.z += u.z; a0.w += u.w;
        a1.x += v.x; a1.y += v.y; a1.z += v.z; a1.w += v.w;
    }
    if (j < end) {
        const int s0 = adj[j];
        const float4 u = *(const float4*)(m1 + (long)s0 * 256 + lane * 4);
        a0.x += u.x; a0.y += u.y; a0.z += u.z; a0.w += u.w;
    }
    float4 v;
    const float4 b = *(const float4*)(b1 + lane * 4);
    v.x = a0.x + a1.x + b.x; v.y = a0.y + a1.y + b.y;
    v.z = a0.z + a1.z + b.z; v.w = a0.w + a1.w + b.w;
    float s  = v.x + v.y + v.z + v.w;
    float sq = v.x * v.x + v.y * v.y + v.z * v.z + v.w * v.w;
    for (int o = 32; o > 0; o >>= 1) {
        s  += __shfl_xor(s, o, 64);
        sq += __shfl_xor(sq, o, 64);
    }
    const float mean = s * (1.0f / 256.0f);
    const float var  = sq * (1.0f / 256.0f) - mean * mean;
    const float rsv = rsqrtf(var + 1e-5f);
    const float4 g  = *(const float4*)(g1 + lane * 4);
    const float4 bt = *(const float4*)(bt1 + lane * 4);
    float4 o4;
    o4.x = fmaxf((v.x - mean) * rsv * g.x + bt.x, 0.f);
    o4.y = fmaxf((v.y - mean) * rsv * g.y + bt.y, 0.f);
    o4.z = fmaxf((v.z - mean) * rsv * g.z + bt.z, 0.f);
    o4.w = fmaxf((v.w - mean) * rsv * g.w + bt.w, 0.f);
    *(float4*)(h1 + (long)n * 256 + lane * 4) = o4;
}

// ---- K4: agg1 = segsum(h1[adj]); gather per node (dim 256) ----
__global__ __launch_bounds__(256) void k_gather256(const float* __restrict__ feat,
                                                   const int* __restrict__ rs,
                                                   const int* __restrict__ adj,
                                                   float* __restrict__ out) {
    const int wid = threadIdx.x >> 6, lane = threadIdx.x & 63;
    const int n = blockIdx.x * 4 + wid;
    const int beg = rs[n], end = rs[n + 1];
    float4 a0 = {0.f,0.f,0.f,0.f}, a1 = {0.f,0.f,0.f,0.f};
    int j = beg;
    for (; j + 1 < end; j += 2) {
        const int s0 = adj[j], s1 = adj[j + 1];
        const float4 u = *(const float4*)(feat + (long)s0 * 256 + lane * 4);
        const float4 v = *(const float4*)(feat + (long)s1 * 256 + lane * 4);
        a0.x += u.x; a0.y += u.y; a0.z += u.z; a0.w += u.w;
        a1.x += v.x; a1.y += v.y; a1.z += v.z; a1.w += v.w;
    }
    if (j < end) {
        const int s0 = adj[j];
        const float4 u = *(const float4*)(feat + (long)s0 * 256 + lane * 4);
        a0.x += u.x; a0.y += u.y; a0.z += u.z; a0.w += u.w;
    }
    float4 o4;
    o4.x = a0.x + a1.x; o4.y = a0.y + a1.y;
    o4.z = a0.z + a1.z; o4.w = a0.w + a1.w;
    *(float4*)(out + (long)n * 256 + lane * 4) = o4;
}

// ------- K5: mu/logvar from agg1, z = mu + eps*exp(lv/2), kl partial -------
__global__ __launch_bounds__(256) void k_mulv(const float* __restrict__ agg1,
                                              const float* __restrict__ Wmu,
                                              const float* __restrict__ bmu,
                                              const float* __restrict__ Wlv,
                                              const float* __restrict__ blv,
                                              const float* __restrict__ eps,
                                              float* __restrict__ z,
                                              double* __restrict__ kl_accum) {
    __shared__ float rows[4 * 256];
    const int tid = threadIdx.x;
    const long base = (long)blockIdx.x * 4 * 256;
    ((float4*)rows)[tid] = ((const float4*)(agg1 + base))[tid];
    __syncthreads();
    const int r = tid >> 6;
    const int c = tid & 63;
    float amu = 0.f, alv = 0.f;
    for (int k = 0; k < 256; k += 4) {
        const float4 a = *(const float4*)&rows[r * 256 + k];
        amu += a.x * Wmu[(k+0)*64+c] + a.y * Wmu[(k+1)*64+c]
             + a.z * Wmu[(k+2)*64+c] + a.w * Wmu[(k+3)*64+c];
        alv += a.x * Wlv[(k+0)*64+c] + a.y * Wlv[(k+1)*64+c]
             + a.z * Wlv[(k+2)*64+c] + a.w * Wlv[(k+3)*64+c];
    }
    const float mu = amu + bmu[c];
    const float lv = alv + blv[c];
    const long i = (long)blockIdx.x * 4 + r;
    const float ev = eps[i * 64 + c];
    z[i * 64 + c] = mu + ev * expf(0.5f * lv);
    float term = 1.0f + lv - mu * mu - expf(lv);
    for (int o = 32; o > 0; o >>= 1) term += __shfl_xor(term, o, 64);
    if (c == 0) atomicAdd(kl_accum, (double)term);
}

// ---- K7a/K8a: normalized gather (dim 64) over pos CSR ----
__global__ __launch_bounds__(256) void k_gather_norm64(const float* __restrict__ feat,
                                                       const int* __restrict__ rs,
                                                       const int* __restrict__ adj,
                                                       const float* __restrict__ dis,
                                                       float* __restrict__ out) {
    const int wid = threadIdx.x >> 6, lane = threadIdx.x & 63;
    const int n = blockIdx.x * 4 + wid;
    const int beg = rs[n], end = rs[n + 1];
    float a0 = 0.f, a1 = 0.f;
    int j = beg;
    for (; j + 1 < end; j += 2) {
        const int s0 = adj[j], s1 = adj[j + 1];
        a0 += feat[(long)s0 * 64 + lane] * dis[s0];
        a1 += feat[(long)s1 * 64 + lane] * dis[s1];
    }
    if (j < end) {
        const int s0 = adj[j];
        a0 += feat[(long)s0 * 64 + lane] * dis[s0];
    }
    out[(long)n * 64 + lane] = (a0 + a1) * dis[n];
}

// --- K7b: hdec = relu((agg + self*dis^2) @ Wd + bd), fp32 out ---
__global__ __launch_bounds__(256) void k_dec_mm(const float* __restrict__ agg,
                                                const float* __restrict__ self_feat,
                                                const float* __restrict__ dis,
                                                const float* __restrict__ Wd,
                                                const float* __restrict__ bd,
                                                float* __restrict__ out) {
    __shared__ float rows[4 * 64];
    __shared__ float sW[64 * 64];
    const int tid = threadIdx.x;
    {
        const float4* w4 = (const float4*)Wd;
        float4* sw4 = (float4*)sW;
        for (int i = tid; i < 1024; i += 256) sw4[i] = w4[i];
    }
    const int r = tid >> 6, c = tid & 63;
    const long i = (long)blockIdx.x * 4 + r;
    const float dsi = dis[i];
    rows[r * 64 + c] = agg[i * 64 + c] + self_feat[i * 64 + c] * dsi * dsi;
    __syncthreads();
    float acc = 0.f;
    for (int k = 0; k < 64; k += 4) {
        const float4 a = *(const float4*)&rows[r * 64 + k];
        acc += a.x * sW[(k+0)*64+c] + a.y * sW[(k+1)*64+c]
             + a.z * sW[(k+2)*64+c] + a.w * sW[(k+3)*64+c];
    }
    out[i * 64 + c] = fmaxf(acc + bd[c], 0.f);
}

// --- K8b: h2bf = bf16(relu((agg + self*dis^2) @ Wd + bd)) ---
__global__ __launch_bounds__(256) void k_dec_mm_bf16(const float* __restrict__ agg,
                                                     const float* __restrict__ self_feat,
                                                     const float* __restrict__ dis,
                                                     const float* __restrict__ Wd,
                                                     const float* __restrict__ bd,
                                                     unsigned short* __restrict__ out) {
    __shared__ float rows[4 * 64];
    __shared__ float sW[64 * 64];
    const int tid = threadIdx.x;
    {
        const float4* w4 = (const float4*)Wd;
        float4* sw4 = (float4*)sW;
        for (int i = tid; i < 1024; i += 256) sw4[i] = w4[i];
    }
    const int r = tid >> 6, c = tid & 63;
    const long i = (long)blockIdx.x * 4 + r;
    const float dsi = dis[i];
    rows[r * 64 + c] = agg[i * 64 + c] + self_feat[i * 64 + c] * dsi * dsi;
    __syncthreads();
    float acc = 0.f;
    for (int k = 0; k < 64; k += 4) {
        const float4 a = *(const float4*)&rows[r * 64 + k];
        acc += a.x * sW[(k+0)*64+c] + a.y * sW[(k+1)*64+c]
             + a.z * sW[(k+2)*64+c] + a.w * sW[(k+3)*64+c];
    }
    out[i * 64 + c] = f2bf(fmaxf(acc + bd[c], 0.f));
}

// ----- K9-prep: WaT[n][k'] = bf16(Wa[k][n]), k' = d*4+part, k = part*64+d -----
__global__ void k_prep_wa(const float* __restrict__ Wa, unsigned short* __restrict__ WaT) {
    const int idx = blockIdx.x * 256 + threadIdx.x;   // 0..16383
    const int n = idx >> 8, kp = idx & 255;
    const int d = kp >> 2, part = kp & 3;
    WaT[idx] = f2bf(Wa[(part * 64 + d) * 64 + n]);
}

// ---------------- K9: edge MLP via MFMA, wave-specialized over N ----------
// Block = 4 waves = 64 edges. Wave w owns hidden cols n = w*16..w*16+15 and
// keeps its WaT slice in 32 VGPRs (B-frags, loaded once). All waves share one
// phi tile [64 edges][256 k] bf16 in LDS (34KB -> 4 blocks/CU); each wave
// builds its 16-edge quarter (coalesced 128B row loads), one barrier, then
// 4 M-tiles x 8 ks MFMAs. Cross-wave n-reduction via LDS float atomics.
__global__ __launch_bounds__(256, 4) void k_edge_mlp_mfma(
        const unsigned short* __restrict__ h2bf,
        const int* __restrict__ pos,
        const int* __restrict__ neg,
        const unsigned short* __restrict__ WaT,
        const float* __restrict__ ba,
        const float* __restrict__ Wb,
        const float* __restrict__ bb,
        const float* __restrict__ tau,
        double* __restrict__ recon_accum) {
    __shared__ unsigned short sPhi[64 * 264];  // 33792 B, +8 pad per row
    __shared__ float sE[64];                   // per-edge partial (over n)
    const int tid = threadIdx.x;
    const int w = tid >> 6, lane = tid & 63;
    const int l15 = lane & 15, quad = lane >> 4;

    // B-frags for this wave's n-slice, kept in registers (once per block)
    bf16x8 breg[8];
#pragma unroll
    for (int ks = 0; ks < 8; ++ks)
        breg[ks] = *(const bf16x8*)&WaT[(w * 16 + l15) * 256 + ks * 32 + quad * 8];

    const float ban = ba[w * 16 + l15];
    const float wbn = Wb[w * 16 + l15];
    const float bb0 = bb[0];
    const float itau = 1.0f / fmaxf(tau[0], 1e-4f);

    if (tid < 64) sE[tid] = 0.f;

    // build this wave's 16-edge quarter of phi
    const long e0 = (long)blockIdx.x * 64 + w * 16;
#pragma unroll
    for (int m = 0; m < 16; ++m) {
        const long j = e0 + m;
        int u, v;
        if (j < EP) { u = pos[j]; v = pos[EP + j]; }
        else        { u = neg[j - EP]; v = neg[ENEG + (j - EP)]; }
        const unsigned hu = h2bf[(long)u * 64 + lane];
        const unsigned hv = h2bf[(long)v * 64 + lane];
        const float fu = __uint_as_float(hu << 16);
        const float fv = __uint_as_float(hv << 16);
        const float ad = fabsf(fu - fv);
        const float pr = fu * fv;
        union { unsigned u32[2]; unsigned long long ll; } pk;
        pk.u32[0] = hu | (hv << 16);                         // k'=d*4+{0,1}
        {
            const __hip_bfloat162 p = __float22bfloat162_rn(float2{ad, pr});
            union { __hip_bfloat162 h; unsigned u; } cc; cc.h = p;
            pk.u32[1] = cc.u;                                // k'=d*4+{2,3}
        }
        *(unsigned long long*)&sPhi[(w * 16 + m) * 264 + lane * 4] = pk.ll;
    }
    __syncthreads();

    // MFMA: D[64 edges][16 n] for this wave's n-slice
    f32x4 acc[4];
#pragma unroll
    for (int mt = 0; mt < 4; ++mt) acc[mt] = (f32x4){0.f, 0.f, 0.f, 0.f};
#pragma unroll
    for (int ks = 0; ks < 8; ++ks) {
#pragma unroll
        for (int mt = 0; mt < 4; ++mt) {
            const bf16x8 af = *(const bf16x8*)&sPhi[(mt * 16 + l15) * 264 +
                                                    ks * 32 + quad * 8];
            acc[mt] = __builtin_amdgcn_mfma_f32_16x16x32_bf16(af, breg[ks], acc[mt], 0, 0, 0);
        }
    }

    // epilogue: relu(+ba)*Wb, reduce over this wave's 16 cols, LDS-atomic
    // into per-edge slot. D row = quad*4 + r, col = l15.
#pragma unroll
    for (int mt = 0; mt < 4; ++mt) {
#pragma unroll
        for (int r = 0; r < 4; ++r) {
            float s = fmaxf(acc[mt][r] + ban, 0.f) * wbn;
            for (int o = 8; o > 0; o >>= 1) s += __shfl_xor(s, o, 64);
            if (l15 == 0) atomicAdd(&sE[mt * 16 + quad * 4 + r], s);
        }
    }
    __syncthreads();

    // wave 0 finishes: logits + weighted BCE for the block's 64 edges
    if (w == 0) {
        const long j = (long)blockIdx.x * 64 + lane;
        const float logit = (sE[lane] + bb0) * itau;
        float lsum = (j < EP) ? 5.0f * logsigf(logit) : logsigf(-logit);
        for (int o = 32; o > 0; o >>= 1) lsum += __shfl_xor(lsum, o, 64);
        if (lane == 0) atomicAdd(recon_accum, (double)lsum);
    }
}

// ---------------- K10: finalize ----------------
__global__ void k_final(const double* __restrict__ accum, float* __restrict__ out) {
    if (threadIdx.x == 0) {
        const double recon = -accum[0] / (double)ETOT;
        const double kl = -0.5 * accum[1] / ((double)N_NODES * 64.0);
        out[0] = (float)(recon + kl);
        out[1] = (float)recon;
        out[2] = (float)kl;
    }
}

extern "C" void kernel_launch(void* const* d_in, const int* in_sizes, int n_in,
                              void* d_out, int out_size, void* d_ws, size_t ws_size,
                              hipStream_t stream) {
    const float* x   = (const float*)d_in[0];
    const float* eps = (const float*)d_in[1];
    const int* EI    = (const int*)d_in[2];   // [2, 240000]
    const int* pos   = (const int*)d_in[3];   // [2, 120000]
    const int* neg   = (const int*)d_in[4];   // [2, 600000]
    const float* W1  = (const float*)d_in[5];
    const float* b1  = (const float*)d_in[6];
    const float* g1  = (const float*)d_in[7];
    const float* bt1 = (const float*)d_in[8];
    const float* Wmu = (const float*)d_in[9];
    const float* bmu = (const float*)d_in[10];
    const float* Wlv = (const float*)d_in[11];
    const float* blv = (const float*)d_in[12];
    const float* Wd1 = (const float*)d_in[13];
    const float* bd1 = (const float*)d_in[14];
    const float* Wd2 = (const float*)d_in[15];
    const float* bd2 = (const float*)d_in[16];
    const float* Wa  = (const float*)d_in[17];
    const float* ba  = (const float*)d_in[18];
    const float* Wb  = (const float*)d_in[19];
    const float* bb  = (const float*)d_in[20];
    const float* tau = (const float*)d_in[21];

    const int* e_src = EI;
    const int* e_dst = EI + E2;
    const int* ps = pos;
    const int* pd = pos + EP;

    // ---- workspace layout (float units) ----
    float* ws = (float*)d_ws;
    float* m1    = ws;                        // [20000,256]  region A
    float* agg1  = ws;                        // A (after m1 dead)
    float* aggz  = ws;                        // A (after agg1 dead)
    float* hdec  = ws + 1280000;              // A
    float* aggh  = ws + 2560000;              // A
    unsigned short* h2bf = (unsigned short*)(ws + 3840000);  // A, bf16 [20000,64]
    float* h1    = ws + 5120000;              // [20000,256]  region B
    float* z     = ws + 10240000;             // [20000,64]
    float* dis   = ws + 11520000;             // [20000]
    double* accum = (double*)(ws + 11540000); // 2 doubles (8B-aligned)
    unsigned short* WaT = (unsigned short*)(ws + 11540004); // [64,256] bf16 (16B-aligned)
    int* cntA = (int*)(ws + 11548200);        // [20000] counts -> cursor
    int* rsA  = (int*)(ws + 11568200);        // [20001]
    int* adjA = (int*)(ws + 11588204);        // [240000]
    int* cntP = (int*)(ws + 11828204);        // [20000]
    int* rsP  = (int*)(ws + 11848204);        // [20001]
    int* adjP = (int*)(ws + 11868208);        // [120000]

    hipMemsetAsync(accum, 0, 16, stream);
    hipMemsetAsync(cntA, 0, N_NODES * 4, stream);
    hipMemsetAsync(cntP, 0, N_NODES * 4, stream);
    k_prep_wa<<<64, 256, 0, stream>>>(Wa, WaT);

    // CSR for undirected message graph (dst <- src over edge_index)
    k_hist<<<(E2 + 255) / 256, 256, 0, stream>>>(e_dst, cntA, E2);
    k_scan<<<1, 1024, 0, stream>>>(cntA, rsA, cntA, N_NODES);
    k_fill<<<(E2 + 255) / 256, 256, 0, stream>>>(e_src, e_dst, cntA, adjA, E2);

    // CSR for positive-edge decoder graph (pd <- ps) + dis
    k_hist<<<(EP + 255) / 256, 256, 0, stream>>>(pd, cntP, EP);
    k_scan<<<1, 1024, 0, stream>>>(cntP, rsP, cntP, N_NODES);
    k_fill<<<(EP + 255) / 256, 256, 0, stream>>>(ps, pd, cntP, adjP, EP);
    k_dis<<<(N_NODES + 255) / 256, 256, 0, stream>>>(rsP, dis);

    // encoder layer 1 (matmul, then fused gather+LN+relu)
    k_mm_xW1<<<2500, 256, 0, stream>>>(x, W1, m1);
    k_gather_ln<<<5000, 256, 0, stream>>>(m1, rsA, adjA, b1, g1, bt1, h1);

    // shared aggregation for mu/logvar, then z + kl
    k_gather256<<<5000, 256, 0, stream>>>(h1, rsA, adjA, agg1);
    k_mulv<<<5000, 256, 0, stream>>>(agg1, Wmu, bmu, Wlv, blv, eps, z, accum + 1);

    // decoder layer 1
    k_gather_norm64<<<5000, 256, 0, stream>>>(z, rsP, adjP, dis, aggz);
    k_dec_mm<<<5000, 256, 0, stream>>>(aggz, z, dis, Wd1, bd1, hdec);

    // decoder layer 2 -> bf16 h2
    k_gather_norm64<<<5000, 256, 0, stream>>>(hdec, rsP, adjP, dis, aggh);
    k_dec_mm_bf16<<<5000, 256, 0, stream>>>(aggh, hdec, dis, Wd2, bd2, h2bf);

    // edge MLP + loss (MFMA, wave-specialized)
    k_edge_mlp_mfma<<<ETOT / 64, 256, 0, stream>>>(h2bf, pos, neg, WaT, ba, Wb, bb, tau, accum);
    k_final<<<1, 64, 0, stream>>>(accum, (float*)d_out);
}